// Round 4
// baseline (118.746 us; speedup 1.0000x reference)
//
#include <hip/hip_runtime.h>
#include <hip/hip_fp16.h>

// Trilinear 3D-LUT interpolation (image-adaptive-3DLUT forward).
// lut: [3, 33, 33, 33] fp32, x: [4, 3, 1024, 1024] fp32 in [0,1], out same as x.
//
// R7: channel-specialized blocks. R6 (~32us kernel) was the SERIAL SUM of its
// barrier-separated phases (x-drain 8us + 3 gather phases + 2 exposed LUT
// switches). This version makes the schedule channel-major:
//  - task space = 3*2^20 (channel, float4-group) pairs, channel-major;
//    grid=256, 12288 contiguous tasks/block -> each block stages its channel
//    ONCE (only 2/256 straddler blocks restage once, block-uniform sync).
//    Zero switches, ONE barrier for 254 blocks.
//  - 6 steps x 2 groups/thread, software-pipelined: issue next step's x loads,
//    then gather/lerp/store current step -> x latency hides under LDS work.
//  - x read 3x device-wide but sweeps are phase-aligned and x is L3-resident
//    (50MB << 256MB, nothing evicts it) -> re-reads hit Infinity Cache.
//  - LUT fp16 pairs packed ALONG B: P[i]=(v[i], v[i+1089]) -> per pixel both
//    ds_read2_b32 (offsets 0/1 and 33/34) share ONE base register.

#define LUT_D     33
#define LUT_DD    (LUT_D * LUT_D)            // 1089
#define LUT_N     (LUT_D * LUT_D * LUT_D)    // 35937
#define CH_STRIDE 35940                      // u32 per channel in ws, 16B-aligned
#define STAGE_G   (CH_STRIDE / 4)            // 8985 dwordx4 groups per channel
#define HW4       (1024 * 1024 / 4)          // 262144 = 2^18 float4/plane
#define NGROUPS   (4 * HW4)                  // 2^20 float4 groups per plane-set
#define THREADS   1024
#define GRID      256
#define GPB       (3 * NGROUPS / GRID)       // 12288 tasks per block
#define STEPS     6                          // 2048 tasks/step = 2 per thread

typedef float vfloat4 __attribute__((ext_vector_type(4)));

__device__ __forceinline__ unsigned int pack2(float a, float b) {
    union { __half2 h; unsigned int u; } cv;
    cv.h = __floats2half2_rn(a, b);
    return cv.u;
}
__device__ __forceinline__ float2 unpack2(unsigned int p) {
    union { unsigned int u; __half2 h; } cv;
    cv.u = p;
    return __half22float2(cv.h);
}

// ---- Pass 1: pack lut fp32 -> fp16 b-pairs: ws[c*CH_STRIDE+i] = (v[i], v[i+1089])
__global__ __launch_bounds__(256)
void lut_pack_kernel(const float* __restrict__ lut, unsigned int* __restrict__ W) {
    const int t = blockIdx.x * 256 + (int)threadIdx.x;
    if (t >= 3 * LUT_N) return;
    const int c = t / LUT_N;
    const int i = t - c * LUT_N;
    const float a = lut[t];
    const float b = (i + LUT_DD < LUT_N) ? lut[t + LUT_DD] : 0.0f;
    W[c * CH_STRIDE + i] = pack2(a, b);
}

// ---- Pass 2: main interpolation, channel-specialized, pipelined.
__global__ __launch_bounds__(THREADS)
void lut3d_trilerp_kernel(const unsigned int* __restrict__ Wsrc,
                          const float* __restrict__ x,
                          float* __restrict__ out) {
    extern __shared__ __align__(16) unsigned int W[];  // CH_STRIDE u32 = 143,760 B

    const int t    = (int)threadIdx.x;
    const int base = (int)blockIdx.x * GPB;            // first task id of block

    const float4* x4 = (const float4*)x;
    float4*       o4 = (float4*)out;

    auto stage = [&](int c) {
#pragma unroll
        for (int s = 0; s < 9; ++s) {
            const int gid = s * THREADS + t;
            if (gid < STAGE_G) {
                __builtin_amdgcn_global_load_lds(
                    (const __attribute__((address_space(1))) void*)(Wsrc + c * CH_STRIDE + gid * 4),
                    (__attribute__((address_space(3))) void*)(W + gid * 4),
                    16, 0, 0);
            }
        }
    };

    float4 xR[2][2], xG[2][2], xB[2][2];   // [parity][group-in-step]
    int    ibs[2][2];

    auto loadg = [&](int s, int m, int p) {
        const int gg  = base + s * 2048 + m * 1024 + t;  // task id
        const int g   = gg & (NGROUPS - 1);              // group within plane-set
        const int bi  = g >> 18;                         // image index
        const int hw4 = g & (HW4 - 1);
        const int ib  = bi * 3 * HW4 + hw4;
        ibs[p][m] = ib;
        xR[p][m] = x4[ib];
        xG[p][m] = x4[ib + HW4];
        xB[p][m] = x4[ib + 2 * HW4];
    };

    auto dog = [&](int m, int p, int ch) {
        const float4 R = xR[p][m], G = xG[p][m], B = xB[p][m];
        const float rr[4] = {R.x, R.y, R.z, R.w};
        const float gw[4] = {G.x, G.y, G.z, G.w};
        const float bw[4] = {B.x, B.y, B.z, B.w};

        int   idx[4];
        float dr[4], dg[4], db[4];
#pragma unroll
        for (int k = 0; k < 4; ++k) {
            const float sr = rr[k] * 32.0f;
            const float sg = gw[k] * 32.0f;
            const float sb = bw[k] * 32.0f;
            const float fr = fminf(fmaxf(floorf(sr), 0.0f), 31.0f);
            const float fg = fminf(fmaxf(floorf(sg), 0.0f), 31.0f);
            const float fb = fminf(fmaxf(floorf(sb), 0.0f), 31.0f);
            dr[k] = sr - fr;
            dg[k] = sg - fg;
            db[k] = sb - fb;
            idx[k] = ((int)fb * LUT_D + (int)fg) * LUT_D + (int)fr;
        }

        // Per pixel: 2 ds_read2_b32 from ONE base (offsets 0/1 and 33/34);
        // each u32 holds the (b, b+1) fp16 pair for one (g, r) corner.
        unsigned int q00[4], q01[4], q10[4], q11[4];
#pragma unroll
        for (int k = 0; k < 4; ++k) {
            q00[k] = W[idx[k]];                  // (g0, r0): (b0, b1)
            q01[k] = W[idx[k] + 1];              // (g0, r1)
            q10[k] = W[idx[k] + LUT_D];          // (g1, r0)
            q11[k] = W[idx[k] + LUT_D + 1];      // (g1, r1)
        }

        float oo[4];
#pragma unroll
        for (int k = 0; k < 4; ++k) {
            const float2 a = unpack2(q00[k]);
            const float2 b = unpack2(q01[k]);
            const float2 c = unpack2(q10[k]);
            const float2 d = unpack2(q11[k]);
            const float v00 = a.x + db[k] * (a.y - a.x);   // b-lerp innermost
            const float v01 = b.x + db[k] * (b.y - b.x);
            const float v10 = c.x + db[k] * (c.y - c.x);
            const float v11 = d.x + db[k] * (d.y - d.x);
            const float v0  = v00 + dr[k] * (v01 - v00);   // r-lerp
            const float v1  = v10 + dr[k] * (v11 - v10);
            oo[k] = v0 + dg[k] * (v1 - v0);                // g-lerp
        }
        vfloat4 v = {oo[0], oo[1], oo[2], oo[3]};
        __builtin_nontemporal_store(v, (vfloat4*)&o4[ibs[p][m] + ch * HW4]);
    };

    // Prologue: stage my channel (DMA), prefetch step 0, one barrier.
    int cur = base >> 20;                 // NGROUPS = 2^20 -> channel = task>>20
    stage(cur);
    loadg(0, 0, 0);
    loadg(0, 1, 0);
    __syncthreads();                      // drains DMA + step-0 x loads

#pragma unroll
    for (int s = 0; s < STEPS; ++s) {
        const int p  = s & 1;
        const int pn = p ^ 1;
        const int ch = (base + s * 2048) >> 20;   // uniform per block-step
        if (ch != cur) {                  // only 2/256 blocks, once each
            __syncthreads();              // all waves done reading old channel
            stage(ch);
            __syncthreads();              // DMA drained -> new channel visible
            cur = ch;
        }
        if (s + 1 < STEPS) {              // prefetch next step under this step
            loadg(s + 1, 0, pn);
            loadg(s + 1, 1, pn);
        }
        dog(0, p, ch);
        dog(1, p, ch);
    }
}

extern "C" void kernel_launch(void* const* d_in, const int* in_sizes, int n_in,
                              void* d_out, int out_size, void* d_ws, size_t ws_size,
                              hipStream_t stream) {
    const float*  lut = (const float*)d_in[0];   // [3, 33, 33, 33]
    const float*  x   = (const float*)d_in[1];   // [4, 3, 1024, 1024]
    float*        out = (float*)d_out;
    unsigned int* W   = (unsigned int*)d_ws;     // 3*CH_STRIDE u32 = 431,280 B

    const int pack_grid = (3 * LUT_N + 255) / 256;   // 422
    lut_pack_kernel<<<pack_grid, 256, 0, stream>>>(lut, W);

    const size_t lds_bytes = (size_t)CH_STRIDE * 4;  // 143,760 B -> 1 block/CU
    lut3d_trilerp_kernel<<<GRID, THREADS, lds_bytes, stream>>>(W, x, out);
}

// Round 5
// 117.037 us; speedup vs baseline: 1.0146x; 1.0146x over previous
//
#include <hip/hip_runtime.h>
#include <hip/hip_fp16.h>

// Trilinear 3D-LUT interpolation (image-adaptive-3DLUT forward).
// lut: [3, 33, 33, 33] fp32, x: [4, 3, 1024, 1024] fp32 in [0,1], out same as x.
//
// R8: R6 structure (x read once, per-channel LDS re-stage) with the serial
// exposure removed. R7 (channel-major) regressed: 3x device x reads cost more
// at L3 than the barriers it saved. Changes vs R6:
//  - prologue barrier drains ONLY the ch0 LUT DMA (~1.5us, ws is L2-hot from
//    the pack kernel) + iter-0 x loads. The remaining x reads stream THROUGH
//    channel 0's compute: issue iter it+1's loads, then gather/lerp iter it.
//    R6's 8us serial x-drain now overlaps ch0's gather work.
//  - persistent per-thread state packed to 36 VGPRs: idx as u16 pairs (max
//    idx 34847 < 2^16), deltas as fp16 pairs (err ~2e-4 << absmax 2e-3).
//    R5/R6 kept 64 fp32 values live at the 128-VGPR cap -> spill traffic.
//  - R7's b-pair LUT layout kept: W[i]=(v[i], v[i+1089]); per pixel both
//    ds_read2_b32 share ONE base register (offsets 0/1 and 33/34).

#define LUT_D     33
#define LUT_DD    (LUT_D * LUT_D)            // 1089
#define LUT_N     (LUT_D * LUT_D * LUT_D)    // 35937
#define CH_STRIDE 35940                      // u32 per channel in ws, 16B-aligned
#define STAGE_G   (CH_STRIDE / 4)            // 8985 dwordx4 groups per channel
#define HW4       (1024 * 1024 / 4)          // 262144 = 2^18 float4/plane
#define NGROUPS   (4 * HW4)                  // 2^20 float4 groups per plane-set
#define NCHUNKS   256
#define THREADS   1024
#define ITERS     (NGROUPS / NCHUNKS / THREADS)  // 4

typedef float vfloat4 __attribute__((ext_vector_type(4)));

__device__ __forceinline__ unsigned int pack2(float a, float b) {
    union { __half2 h; unsigned int u; } cv;
    cv.h = __floats2half2_rn(a, b);
    return cv.u;
}
__device__ __forceinline__ float2 unpack2(unsigned int p) {
    union { unsigned int u; __half2 h; } cv;
    cv.u = p;
    return __half22float2(cv.h);
}

// ---- Pass 1: pack lut fp32 -> fp16 b-pairs: ws[c*CH_STRIDE+i] = (v[i], v[i+1089])
__global__ __launch_bounds__(256)
void lut_pack_kernel(const float* __restrict__ lut, unsigned int* __restrict__ W) {
    const int t = blockIdx.x * 256 + (int)threadIdx.x;
    if (t >= 3 * LUT_N) return;
    const int c = t / LUT_N;
    const int i = t - c * LUT_N;
    const float a = lut[t];
    const float b = (i + LUT_DD < LUT_N) ? lut[t + LUT_DD] : 0.0f;
    W[c * CH_STRIDE + i] = pack2(a, b);
}

// ---- Pass 2: main interpolation, one block per chunk, x streamed under ch0.
__global__ __launch_bounds__(THREADS)
void lut3d_trilerp_kernel(const unsigned int* __restrict__ Wsrc,
                          const float* __restrict__ x,
                          float* __restrict__ out) {
    extern __shared__ __align__(16) unsigned int W[];  // CH_STRIDE u32 = 143,760 B

    const int t  = (int)threadIdx.x;
    const int g0 = (int)blockIdx.x * (NGROUPS / NCHUNKS) + t;

    const float4* x4 = (const float4*)x;
    float4*       o4 = (float4*)out;

    auto stage = [&](int c) {
#pragma unroll
        for (int s = 0; s < 9; ++s) {
            const int gid = s * THREADS + t;
            if (gid < STAGE_G) {
                __builtin_amdgcn_global_load_lds(
                    (const __attribute__((address_space(1))) void*)(Wsrc + c * CH_STRIDE + gid * 4),
                    (__attribute__((address_space(3))) void*)(W + gid * 4),
                    16, 0, 0);
            }
        }
    };

    // gather + lerp + store one pixel-quad (all indices compile-time in callers)
    auto quad = [&](const int idx[4], const float dr4[4], const float dg4[4],
                    const float db4[4], int obase) {
        unsigned int q00[4], q01[4], q10[4], q11[4];
#pragma unroll
        for (int k = 0; k < 4; ++k) {
            q00[k] = W[idx[k]];                 // (g0,r0): (b0,b1) fp16 pair
            q01[k] = W[idx[k] + 1];             // (g0,r1)
            q10[k] = W[idx[k] + LUT_D];         // (g1,r0)
            q11[k] = W[idx[k] + LUT_D + 1];     // (g1,r1)
        }
        float oo[4];
#pragma unroll
        for (int k = 0; k < 4; ++k) {
            const float2 a = unpack2(q00[k]);
            const float2 b = unpack2(q01[k]);
            const float2 c = unpack2(q10[k]);
            const float2 d = unpack2(q11[k]);
            const float v00 = a.x + db4[k] * (a.y - a.x);   // b-lerp innermost
            const float v01 = b.x + db4[k] * (b.y - b.x);
            const float v10 = c.x + db4[k] * (c.y - c.x);
            const float v11 = d.x + db4[k] * (d.y - d.x);
            const float v0  = v00 + dr4[k] * (v01 - v00);   // r-lerp
            const float v1  = v10 + dr4[k] * (v11 - v10);
            oo[k] = v0 + dg4[k] * (v1 - v0);                // g-lerp
        }
        vfloat4 v = {oo[0], oo[1], oo[2], oo[3]};
        __builtin_nontemporal_store(v, (vfloat4*)&o4[obase]);
    };

    // ---- Prologue: ch0 DMA + iter-0 x loads in flight together, one barrier.
    stage(0);
    int    ibs[ITERS];
    float4 R[ITERS], G[ITERS], B[ITERS];
    {
        const int bi = g0 >> 18, hw4 = g0 & (HW4 - 1);
        ibs[0] = bi * 3 * HW4 + hw4;
        R[0] = x4[ibs[0]];
        G[0] = x4[ibs[0] + HW4];
        B[0] = x4[ibs[0] + 2 * HW4];
    }
    __syncthreads();   // drains DMA (L2-hot, ~1.5us) + iter-0 x only

    // Persistent packed state: 8 (idx) + 24 (deltas) + 4 (ibs) VGPRs.
    unsigned int pidx[ITERS][2], pdr[ITERS][2], pdg[ITERS][2], pdb[ITERS][2];

    // ---- Channel 0: x streamed (issue it+1, compute it).
#pragma unroll
    for (int it = 0; it < ITERS; ++it) {
        if (it + 1 < ITERS) {
            const int g  = g0 + (it + 1) * THREADS;
            const int bi = g >> 18, hw4 = g & (HW4 - 1);
            ibs[it + 1] = bi * 3 * HW4 + hw4;
            R[it + 1] = x4[ibs[it + 1]];
            G[it + 1] = x4[ibs[it + 1] + HW4];
            B[it + 1] = x4[ibs[it + 1] + 2 * HW4];
        }
        const float rr[4] = {R[it].x, R[it].y, R[it].z, R[it].w};
        const float gw[4] = {G[it].x, G[it].y, G[it].z, G[it].w};
        const float bw[4] = {B[it].x, B[it].y, B[it].z, B[it].w};

        int idx[4]; float dr4[4], dg4[4], db4[4];
#pragma unroll
        for (int k = 0; k < 4; ++k) {
            const float sr = rr[k] * 32.0f;
            const float sg = gw[k] * 32.0f;
            const float sb = bw[k] * 32.0f;
            const float fr = fminf(fmaxf(floorf(sr), 0.0f), 31.0f);
            const float fg = fminf(fmaxf(floorf(sg), 0.0f), 31.0f);
            const float fb = fminf(fmaxf(floorf(sb), 0.0f), 31.0f);
            dr4[k] = sr - fr;
            dg4[k] = sg - fg;
            db4[k] = sb - fb;
            idx[k] = ((int)fb * LUT_D + (int)fg) * LUT_D + (int)fr;
        }
        pidx[it][0] = (unsigned)idx[0] | ((unsigned)idx[1] << 16);
        pidx[it][1] = (unsigned)idx[2] | ((unsigned)idx[3] << 16);
        pdr[it][0] = pack2(dr4[0], dr4[1]);  pdr[it][1] = pack2(dr4[2], dr4[3]);
        pdg[it][0] = pack2(dg4[0], dg4[1]);  pdg[it][1] = pack2(dg4[2], dg4[3]);
        pdb[it][0] = pack2(db4[0], db4[1]);  pdb[it][1] = pack2(db4[2], db4[3]);

        quad(idx, dr4, dg4, db4, ibs[it]);   // channel 0 plane
    }

    // ---- Channels 1, 2: re-stage LDS, replay packed state.
#pragma unroll
    for (int c = 1; c < 3; ++c) {
        __syncthreads();   // all gathers of previous channel done
        stage(c);
        __syncthreads();   // DMA drained -> channel c visible

#pragma unroll
        for (int it = 0; it < ITERS; ++it) {
            const int idx[4] = {(int)(pidx[it][0] & 0xffffu), (int)(pidx[it][0] >> 16),
                                (int)(pidx[it][1] & 0xffffu), (int)(pidx[it][1] >> 16)};
            const float2 r0 = unpack2(pdr[it][0]), r1 = unpack2(pdr[it][1]);
            const float2 gg = unpack2(pdg[it][0]), g1 = unpack2(pdg[it][1]);
            const float2 b0 = unpack2(pdb[it][0]), b1 = unpack2(pdb[it][1]);
            const float dr4[4] = {r0.x, r0.y, r1.x, r1.y};
            const float dg4[4] = {gg.x, gg.y, g1.x, g1.y};
            const float db4[4] = {b0.x, b0.y, b1.x, b1.y};
            quad(idx, dr4, dg4, db4, ibs[it] + c * HW4);
        }
    }
}

extern "C" void kernel_launch(void* const* d_in, const int* in_sizes, int n_in,
                              void* d_out, int out_size, void* d_ws, size_t ws_size,
                              hipStream_t stream) {
    const float*  lut = (const float*)d_in[0];   // [3, 33, 33, 33]
    const float*  x   = (const float*)d_in[1];   // [4, 3, 1024, 1024]
    float*        out = (float*)d_out;
    unsigned int* W   = (unsigned int*)d_ws;     // 3*CH_STRIDE u32 = 431,280 B

    const int pack_grid = (3 * LUT_N + 255) / 256;   // 422
    lut_pack_kernel<<<pack_grid, 256, 0, stream>>>(lut, W);

    const size_t lds_bytes = (size_t)CH_STRIDE * 4;  // 143,760 B -> 1 block/CU
    lut3d_trilerp_kernel<<<NCHUNKS, THREADS, lds_bytes, stream>>>(W, x, out);
}

// Round 6
// 114.107 us; speedup vs baseline: 1.0407x; 1.0257x over previous
//
#include <hip/hip_runtime.h>
#include <hip/hip_fp16.h>

// Trilinear 3D-LUT interpolation (image-adaptive-3DLUT forward).
// lut: [3, 33, 33, 33] fp32, x: [4, 3, 1024, 1024] fp32 in [0,1], out same as x.
//
// R9: R6 (best, 112.2us) + ONE change: counted-vmcnt prologue (T4).
// R6's first __syncthreads forced vmcnt(0) on all 12 hoisted x loads -> the
// whole 50MB device x read (~8us/CU) was a serial prefix before any gather.
// Now: issue ch0 LUT DMA FIRST (9 global_load_lds), then the 12 x loads, then
//   s_waitcnt vmcnt(12)   -> drains ONLY the 9 oldest ops (the DMA)
//   s_barrier             -> LDS visible to all waves; x still in flight
// Channel-0 then computes idx/gathers per-iteration; the compiler's
// per-register counted waits stagger x consumption, so gathers start as soon
// as iter-0's x lands and the x read streams under ch0's LDS+VALU work.
// sched_barrier(0) pins issue order (rule #18/#21): if any x load sank below
// the waitcnt, vmcnt(12) would no longer cover all DMA -> race.
// R8's other changes (packed state, b-pair layout, per-iter load issue)
// regressed and are reverted: everything below except the prologue is R6.

#define LUT_D     33
#define LUT_DD    (LUT_D * LUT_D)            // 1089
#define LUT_N     (LUT_D * LUT_D * LUT_D)    // 35937
#define CH_STRIDE 35940                      // u32 per channel in ws, 16B-aligned
#define STAGE_G   (CH_STRIDE / 4)            // 8985 dwordx4 groups per channel
#define HW4       (1024 * 1024 / 4)          // 262144 = 2^18 float4/plane
#define NGROUPS   (4 * HW4)                  // 2^20 float4 groups per plane-set
#define NCHUNKS   256
#define THREADS   1024
#define ITERS     (NGROUPS / NCHUNKS / THREADS)  // 4

typedef float vfloat4 __attribute__((ext_vector_type(4)));

__device__ __forceinline__ unsigned int pack2(float a, float b) {
    union { __half2 h; unsigned int u; } cv;
    cv.h = __floats2half2_rn(a, b);
    return cv.u;
}
__device__ __forceinline__ float2 unpack2(unsigned int p) {
    union { unsigned int u; __half2 h; } cv;
    cv.u = p;
    return __half22float2(cv.h);
}

// ---- Pass 1: pack lut fp32 -> fp16 r-pairs: ws[c*CH_STRIDE+i] = (v[i], v[i+1])
__global__ __launch_bounds__(256)
void lut_pack_kernel(const float* __restrict__ lut, unsigned int* __restrict__ W) {
    const int t = blockIdx.x * 256 + (int)threadIdx.x;
    if (t >= 3 * LUT_N) return;
    const int c = t / LUT_N;
    const int i = t - c * LUT_N;
    const float a = lut[t];
    const float b = (i + 1 < LUT_N) ? lut[t + 1] : 0.0f;
    W[c * CH_STRIDE + i] = pack2(a, b);
}

// ---- Pass 2: main interpolation, one block per chunk (1 block/CU).
__global__ __launch_bounds__(THREADS)
void lut3d_trilerp_kernel(const unsigned int* __restrict__ Wsrc,
                          const float* __restrict__ x,
                          float* __restrict__ out) {
    extern __shared__ __align__(16) unsigned int W[];  // CH_STRIDE u32 = 143,760 B

    const int t  = (int)threadIdx.x;
    const int g0 = (int)blockIdx.x * (NGROUPS / NCHUNKS) + t;

    const float4* x4 = (const float4*)x;
    float4*       o4 = (float4*)out;

    auto stage = [&](int c) {
#pragma unroll
        for (int s = 0; s < 9; ++s) {
            const int gid = s * THREADS + t;
            if (gid < STAGE_G) {
                __builtin_amdgcn_global_load_lds(
                    (const __attribute__((address_space(1))) void*)(Wsrc + c * CH_STRIDE + gid * 4),
                    (__attribute__((address_space(3))) void*)(W + gid * 4),
                    16, 0, 0);
            }
        }
    };

    // gather + lerp + store one pixel-quad (indices compile-time in callers)
    auto quad = [&](const int idx[4], const float dr4[4], const float dg4[4],
                    const float db4[4], int obase) {
        unsigned int q00[4], q01[4], q10[4], q11[4];
#pragma unroll
        for (int k = 0; k < 4; ++k) {
            q00[k] = W[idx[k]];                  // (c000, c001) r-pair
            q01[k] = W[idx[k] + LUT_D];          // (c010, c011)
            q10[k] = W[idx[k] + LUT_DD];         // (c100, c101)
            q11[k] = W[idx[k] + LUT_DD + LUT_D]; // (c110, c111)
        }
        float oo[4];
#pragma unroll
        for (int k = 0; k < 4; ++k) {
            const float2 a00 = unpack2(q00[k]);
            const float2 a01 = unpack2(q01[k]);
            const float2 a10 = unpack2(q10[k]);
            const float2 a11 = unpack2(q11[k]);
            const float l00 = a00.x + dr4[k] * (a00.y - a00.x);  // r-lerp
            const float l01 = a01.x + dr4[k] * (a01.y - a01.x);
            const float l10 = a10.x + dr4[k] * (a10.y - a10.x);
            const float l11 = a11.x + dr4[k] * (a11.y - a11.x);
            const float l0  = l00 + dg4[k] * (l01 - l00);        // g-lerp
            const float l1  = l10 + dg4[k] * (l11 - l10);
            oo[k] = l0 + db4[k] * (l1 - l0);                     // b-lerp
        }
        vfloat4 v = {oo[0], oo[1], oo[2], oo[3]};
        __builtin_nontemporal_store(v, (vfloat4*)&o4[obase]);
    };

    // ---- Prologue: DMA first, x loads second, counted-vmcnt barrier.
    stage(0);                              // 9 oldest VMEM ops = LUT DMA
    __builtin_amdgcn_sched_barrier(0);     // x loads must not move above DMA

    int    ibs[ITERS];
    float4 R[ITERS], G[ITERS], B[ITERS];
#pragma unroll
    for (int it = 0; it < ITERS; ++it) {
        const int g  = g0 + it * THREADS;
        const int bi = g >> 18, hw4 = g & (HW4 - 1);
        ibs[it] = bi * 3 * HW4 + hw4;
        R[it] = x4[ibs[it]];
        G[it] = x4[ibs[it] + HW4];
        B[it] = x4[ibs[it] + 2 * HW4];
    }
    __builtin_amdgcn_sched_barrier(0);     // x loads must not sink below wait
    asm volatile("s_waitcnt vmcnt(12)" ::: "memory");  // 9 DMA done; 12 x in flight
    __builtin_amdgcn_s_barrier();          // W[ch0] visible to all waves
    __builtin_amdgcn_sched_barrier(0);     // no LDS read hoists above barrier

    // ---- Channel 0: per-iter idx+deltas (compiler staggers x waits) + gather.
    int   idx[ITERS][4];
    float dr[ITERS][4], dg[ITERS][4], db[ITERS][4];
#pragma unroll
    for (int it = 0; it < ITERS; ++it) {
        const float rr[4] = {R[it].x, R[it].y, R[it].z, R[it].w};
        const float gw[4] = {G[it].x, G[it].y, G[it].z, G[it].w};
        const float bw[4] = {B[it].x, B[it].y, B[it].z, B[it].w};
#pragma unroll
        for (int k = 0; k < 4; ++k) {
            const float sr = rr[k] * 32.0f;
            const float sg = gw[k] * 32.0f;
            const float sb = bw[k] * 32.0f;
            const float fr = fminf(fmaxf(floorf(sr), 0.0f), 31.0f);
            const float fg = fminf(fmaxf(floorf(sg), 0.0f), 31.0f);
            const float fb = fminf(fmaxf(floorf(sb), 0.0f), 31.0f);
            dr[it][k] = sr - fr;
            dg[it][k] = sg - fg;
            db[it][k] = sb - fb;
            idx[it][k] = ((int)fb * LUT_D + (int)fg) * LUT_D + (int)fr;
        }
        quad(idx[it], dr[it], dg[it], db[it], ibs[it]);   // channel 0 plane
    }

    // ---- Channels 1, 2: re-stage LDS (proven R6 switch), replay state.
#pragma unroll
    for (int c = 1; c < 3; ++c) {
        __syncthreads();   // all waves done reading previous channel
        stage(c);
        __syncthreads();   // DMA drained -> channel c visible
#pragma unroll
        for (int it = 0; it < ITERS; ++it) {
            quad(idx[it], dr[it], dg[it], db[it], ibs[it] + c * HW4);
        }
    }
}

extern "C" void kernel_launch(void* const* d_in, const int* in_sizes, int n_in,
                              void* d_out, int out_size, void* d_ws, size_t ws_size,
                              hipStream_t stream) {
    const float*  lut = (const float*)d_in[0];   // [3, 33, 33, 33]
    const float*  x   = (const float*)d_in[1];   // [4, 3, 1024, 1024]
    float*        out = (float*)d_out;
    unsigned int* W   = (unsigned int*)d_ws;     // 3*CH_STRIDE u32 = 431,280 B

    const int pack_grid = (3 * LUT_N + 255) / 256;   // 422
    lut_pack_kernel<<<pack_grid, 256, 0, stream>>>(lut, W);

    const size_t lds_bytes = (size_t)CH_STRIDE * 4;  // 143,760 B -> 1 block/CU
    lut3d_trilerp_kernel<<<NCHUNKS, THREADS, lds_bytes, stream>>>(W, x, out);
}